// Round 7
// baseline (1100.103 us; speedup 1.0000x reference)
//
#include <hip/hip_runtime.h>

constexpr int LDIM  = 128;
constexpr int NNODE = 20000;
constexpr int EM_N  = 100000;
constexpr int EW_N  = 25000;
constexpr int NSTEP = 6;

typedef short bf16x8 __attribute__((ext_vector_type(8)));
typedef short bf16x4 __attribute__((ext_vector_type(4)));
typedef float f32x4  __attribute__((ext_vector_type(4)));

struct MlpParams {
  const float* x;
  const float* attrIn;
  float*       attrOut;
  const int*   src;
  const int*   dst;
  float*       sum1;    // edge: scatter target; node: mesh sum (zeroed after read)
  float*       sum2;    // node: world sum (zeroed after read)
  const float* inv1;
  const float* inv2;
  const short* W1H;     // bf16 [128 n][384 k]
  const short* W2H;     // bf16 hi [128 n][128 k]
  const short* W2L;     // bf16 lo
  const float* b1;
  const float* b2;
  const float* gam;
  const float* bet;
  int nRows;
};

__device__ __forceinline__ short f2b(float f) {
  unsigned int u = __float_as_uint(f);
  u = (u + 0x7fffu + ((u >> 16) & 1u)) >> 16;
  return (short)u;
}
__device__ __forceinline__ float b2f(short s) {
  return __uint_as_float(((unsigned int)(unsigned short)s) << 16);
}
__device__ __forceinline__ bf16x4 cvt4(float4 a, float sc) {
  bf16x4 o;
  o[0] = f2b(a.x * sc); o[1] = f2b(a.y * sc);
  o[2] = f2b(a.z * sc); o[3] = f2b(a.w * sc);
  return o;
}

// R6 structure, one change: no full Hbuf. Phase 2 stages H per 32-k chunk
// (10 KB Hch) written directly from the phase-1 accumulators (b1+ReLU fused
// into the write) by the two owner waves (wcc == kc>>1). LDS 71.7->49 KB =>
// 3 blocks/CU instead of 2. W1 (hi) + W2 (hi+lo) LDS staging, named-register
// prefetch, f32 LN epilogue — all unchanged from R6 (validated).
template<bool IS_EDGE>
__launch_bounds__(256, 3)
__global__ void mlp_kernel(MlpParams pmA, MlpParams pmB, int blocksA) {
  const bool isA = (int)blockIdx.x < blocksA;
  const MlpParams P = isA ? pmA : pmB;
  const int bid  = isA ? (int)blockIdx.x : (int)blockIdx.x - blocksA;
  const int row0 = bid * 128;

  __shared__ __align__(16) short Abuf[128][40];   // stride 80B: aligned + 2-way banks
  __shared__ __align__(16) short Bhi[128][40];
  __shared__ __align__(16) short Blo[128][40];
  __shared__ __align__(16) short Hch[128][40];    // one 32-k chunk of H
  __shared__ float b1s[128], b2s[128], gs[128], bes[128];
  __shared__ int   idxa[128], idxb[128];
  __shared__ float inv1s[128], inv2s[128];
  __shared__ float sumL[2][128], sqL[2][128];
  __shared__ float muL[128], rsL[128];

  const int t = threadIdx.x;

  if (t < 128) {
    b1s[t] = P.b1[t];
    gs[t]  = P.gam[t];
    if (IS_EDGE) {
      int r = row0 + t;
      idxa[t] = (r < P.nRows) ? P.src[r] : 0;
    } else {
      int r = min(row0 + t, P.nRows - 1);
      inv1s[t] = P.inv1[r];
    }
  } else {
    int t2 = t - 128;
    b2s[t2] = P.b2[t2];
    bes[t2] = P.bet[t2];
    if (IS_EDGE) {
      int r = row0 + t2;
      idxb[t2] = (r < P.nRows) ? P.dst[r] : 0;
    } else {
      int r = min(row0 + t2, P.nRows - 1);
      inv2s[t2] = P.inv2[r];
    }
  }
  __syncthreads();   // idx/inv tables ready (needed for prefetch base setup)

  const int l   = t & 63;
  const int wid = t >> 6;
  const int wr  = wid >> 1, wcc = wid & 1;
  const int lr  = l & 15,  lg  = l >> 4;

  const int  srow  = t >> 1, sh = t & 1;   // staging row assignment (2 thr/row)
  const int  sgRow = row0 + srow;
  const bool sval  = sgRow < P.nRows;
  const int  sgC   = sval ? sgRow : 0;
  const float vmask = sval ? 1.f : 0.f;

  // per-thread A base pointers for the 3 input segments (incl. sh offset)
  const float* base0; const float* base1; const float* base2;
  float sc1v = vmask, sc2v = vmask;
  if (IS_EDGE) {
    base0 = P.x + (size_t)idxa[srow] * LDIM + sh * 16;
    base1 = P.x + (size_t)idxb[srow] * LDIM + sh * 16;
    base2 = P.attrIn + (size_t)sgC * LDIM + sh * 16;
  } else {
    base0 = P.x    + (size_t)sgC * LDIM + sh * 16;
    base1 = P.sum1 + (size_t)sgC * LDIM + sh * 16;
    base2 = P.sum2 + (size_t)sgC * LDIM + sh * 16;
    sc1v = inv1s[srow] * vmask;
    sc2v = inv2s[srow] * vmask;
  }

  // weight staging assignment (2 thr/row over 128 n-rows)
  const int wrow = t >> 1, wsh = t & 1;
  const short* w1base = P.W1H + (size_t)wrow * 384 + wsh * 16;

  f32x4 acc[4][4];
#pragma unroll
  for (int i = 0; i < 4; ++i)
#pragma unroll
    for (int j = 0; j < 4; ++j) acc[i][j] = f32x4{0.f, 0.f, 0.f, 0.f};

  // named prefetch registers
  float4 pA0, pA1, pA2, pA3;
  bf16x8 pW0, pW1;
  {
    const float4* bp = (const float4*)base0;
    pA0 = bp[0]; pA1 = bp[1]; pA2 = bp[2]; pA3 = bp[3];
    pW0 = *(const bf16x8*)w1base;
    pW1 = *(const bf16x8*)(w1base + 8);
  }

  // ---------------- phase 1: H = relu(A @ W1 + b1), K = 384 ----------------
#pragma unroll
  for (int kc = 0; kc < 12; ++kc) {
    const int seg = kc >> 2, part = kc & 3;
    if (kc > 0) __syncthreads();          // staging buffers free
    {
      const float scK = (seg == 0) ? vmask : (seg == 1) ? sc1v : sc2v;
      *(bf16x4*)&Abuf[srow][sh * 16 + 0]  = cvt4(pA0, scK);
      *(bf16x4*)&Abuf[srow][sh * 16 + 4]  = cvt4(pA1, scK);
      *(bf16x4*)&Abuf[srow][sh * 16 + 8]  = cvt4(pA2, scK);
      *(bf16x4*)&Abuf[srow][sh * 16 + 12] = cvt4(pA3, scK);
      *(bf16x8*)&Bhi[wrow][wsh * 16]     = pW0;
      *(bf16x8*)&Bhi[wrow][wsh * 16 + 8] = pW1;
      if constexpr (!IS_EDGE) {
        if (seg != 0 && sval) {           // zero-after-read (value already in regs)
          float4 z = {0.f, 0.f, 0.f, 0.f};
          float4* zp = (float4*)((seg == 1 ? base1 : base2) + part * 32);
          zp[0] = z; zp[1] = z; zp[2] = z; zp[3] = z;
        }
      }
    }
    __syncthreads();                      // data ready
    if (kc < 11) {                        // issue next-chunk loads; fly over MFMAs
      const int kn = kc + 1, segn = kn >> 2, partn = kn & 3;
      const float4* bp = (const float4*)((segn == 0 ? base0 : segn == 1 ? base1 : base2) + partn * 32);
      pA0 = bp[0]; pA1 = bp[1]; pA2 = bp[2]; pA3 = bp[3];
      pW0 = *(const bf16x8*)(w1base + kn * 32);
      pW1 = *(const bf16x8*)(w1base + kn * 32 + 8);
    }
    bf16x8 av[4], bh[4];
#pragma unroll
    for (int mi = 0; mi < 4; ++mi)
      av[mi] = *(const bf16x8*)&Abuf[wr * 64 + mi * 16 + lr][lg * 8];
#pragma unroll
    for (int ni = 0; ni < 4; ++ni)
      bh[ni] = *(const bf16x8*)&Bhi[wcc * 64 + ni * 16 + lr][lg * 8];
#pragma unroll
    for (int mi = 0; mi < 4; ++mi)
#pragma unroll
      for (int ni = 0; ni < 4; ++ni)
        acc[mi][ni] = __builtin_amdgcn_mfma_f32_16x16x32_bf16(av[mi], bh[ni], acc[mi][ni], 0, 0, 0);
  }

  // ---------------- phase 2: OUT = H @ W2 + b2, K = 128 (H chunked from acc) ----------------
  f32x4 acc2[4][4];
#pragma unroll
  for (int i = 0; i < 4; ++i)
#pragma unroll
    for (int j = 0; j < 4; ++j) acc2[i][j] = f32x4{0.f, 0.f, 0.f, 0.f};

  const short* w2hbase = P.W2H + (size_t)wrow * 128 + wsh * 16;
  const short* w2lbase = P.W2L + (size_t)wrow * 128 + wsh * 16;

  bf16x8 qh0, qh1, ql0, ql1;
  qh0 = *(const bf16x8*)w2hbase;
  qh1 = *(const bf16x8*)(w2hbase + 8);
  ql0 = *(const bf16x8*)w2lbase;
  ql1 = *(const bf16x8*)(w2lbase + 8);

#pragma unroll
  for (int kc = 0; kc < 4; ++kc) {
    __syncthreads();   // kc=0: phase-1 LDS readers done; else prev chunk readers done
    {
      // stage W2 chunk
      *(bf16x8*)&Bhi[wrow][wsh * 16]     = qh0;
      *(bf16x8*)&Bhi[wrow][wsh * 16 + 8] = qh1;
      *(bf16x8*)&Blo[wrow][wsh * 16]     = ql0;
      *(bf16x8*)&Blo[wrow][wsh * 16 + 8] = ql1;
      // owner waves (wcc == kc>>1) write H chunk cols kc*32..+32 from acc,
      // fusing b1 + ReLU + bf16 round. Rows: wr=0 covers 0..63, wr=1 covers 64..127.
      if (wcc == (kc >> 1)) {
        const int c0 = (kc & 1) * 2;
#pragma unroll
        for (int rt = 0; rt < 4; ++rt)
#pragma unroll
          for (int ci = 0; ci < 2; ++ci) {
            const int ct = c0 + ci;
            const float bb = b1s[wcc * 64 + ct * 16 + lr];
#pragma unroll
            for (int q = 0; q < 4; ++q) {
              const int rr = wr * 64 + rt * 16 + lg * 4 + q;
              Hch[rr][ci * 16 + lr] = f2b(fmaxf(acc[rt][ct][q] + bb, 0.f));
            }
          }
      }
    }
    __syncthreads();   // chunk ready
    if (kc < 3) {
      qh0 = *(const bf16x8*)(w2hbase + (kc + 1) * 32);
      qh1 = *(const bf16x8*)(w2hbase + (kc + 1) * 32 + 8);
      ql0 = *(const bf16x8*)(w2lbase + (kc + 1) * 32);
      ql1 = *(const bf16x8*)(w2lbase + (kc + 1) * 32 + 8);
    }
    bf16x8 av2[4], bh2[4], bl2[4];
#pragma unroll
    for (int rt = 0; rt < 4; ++rt)
      av2[rt] = *(const bf16x8*)&Hch[wr * 64 + rt * 16 + lr][lg * 8];
#pragma unroll
    for (int ct = 0; ct < 4; ++ct) {
      bh2[ct] = *(const bf16x8*)&Bhi[wcc * 64 + ct * 16 + lr][lg * 8];
      bl2[ct] = *(const bf16x8*)&Blo[wcc * 64 + ct * 16 + lr][lg * 8];
    }
#pragma unroll
    for (int rt = 0; rt < 4; ++rt)
#pragma unroll
      for (int ct = 0; ct < 4; ++ct) {
        acc2[rt][ct] = __builtin_amdgcn_mfma_f32_16x16x32_bf16(av2[rt], bl2[ct], acc2[rt][ct], 0, 0, 0);
        acc2[rt][ct] = __builtin_amdgcn_mfma_f32_16x16x32_bf16(av2[rt], bh2[ct], acc2[rt][ct], 0, 0, 0);
      }
  }

  // ---------------- f32 epilogue: b2 + LN stats from registers ----------------
  float s1[4][4], s2[4][4];
#pragma unroll
  for (int rt = 0; rt < 4; ++rt)
#pragma unroll
    for (int q = 0; q < 4; ++q) { s1[rt][q] = 0.f; s2[rt][q] = 0.f; }
#pragma unroll
  for (int rt = 0; rt < 4; ++rt)
#pragma unroll
    for (int ct = 0; ct < 4; ++ct) {
      const float bb = b2s[wcc * 64 + ct * 16 + lr];
#pragma unroll
      for (int q = 0; q < 4; ++q) {
        float v = acc2[rt][ct][q] + bb;
        acc2[rt][ct][q] = v;
        s1[rt][q] += v;
        s2[rt][q] += v * v;
      }
    }
#pragma unroll
  for (int m = 1; m < 16; m <<= 1) {
#pragma unroll
    for (int rt = 0; rt < 4; ++rt)
#pragma unroll
      for (int q = 0; q < 4; ++q) {
        s1[rt][q] += __shfl_xor(s1[rt][q], m);
        s2[rt][q] += __shfl_xor(s2[rt][q], m);
      }
  }
  __syncthreads();
  {
    const int rt = lr >> 2, q = lr & 3;
    const int rr = wr * 64 + rt * 16 + lg * 4 + q;
    sumL[wcc][rr] = s1[rt][q];
    sqL[wcc][rr]  = s2[rt][q];
  }
  __syncthreads();
  if (t < 128) {
    const float tot = sumL[0][t] + sumL[1][t];
    const float tsq = sqL[0][t] + sqL[1][t];
    const float mu  = tot * (1.0f / 128.0f);
    const float var = tsq * (1.0f / 128.0f) - mu * mu;
    muL[t] = mu;
    rsL[t] = rsqrtf(var + 1e-5f);
  }
  __syncthreads();

  // ---------------- normalize + residual + store + (edge) scatter-add ----------------
#pragma unroll
  for (int rt = 0; rt < 4; ++rt) {
#pragma unroll
    for (int q = 0; q < 4; ++q) {
      const int rr = wr * 64 + rt * 16 + lg * 4 + q;
      const int grow = row0 + rr;
      if (grow < P.nRows) {
        const float mu = muL[rr], rs = rsL[rr];
        const float* rin = P.attrIn + (size_t)grow * LDIM;
        float* rout = P.attrOut + (size_t)grow * LDIM;
        float* ssum = nullptr;
        if (IS_EDGE) ssum = P.sum1 + (size_t)idxb[rr] * LDIM;
#pragma unroll
        for (int ct = 0; ct < 4; ++ct) {
          const int cc = wcc * 64 + ct * 16 + lr;
          const float o = gs[cc] * (acc2[rt][ct][q] - mu) * rs + bes[cc] + rin[cc];
          rout[cc] = o;
          if (IS_EDGE) atomicAdd(ssum + cc, o);
        }
      }
    }
  }
}

// ---- prep kernels ----
__global__ void prep_weights(const float* w1a, const float* w1b, const float* w1c,
                             const float* w2a, const float* w2b, const float* w2c,
                             short* w1h, short* w2h, short* w2l) {
  int i = blockIdx.x * 256 + threadIdx.x;
  constexpr int N1 = 18 * 128 * 384;
  constexpr int N2 = 18 * 128 * 128;
  if (i < N1) {
    int g = i / (128 * 384);
    int rem = i - g * (128 * 384);
    int n = rem / 384, k = rem - n * 384;
    int m = g / 6, s = g - m * 6;
    const float* src = (m == 0) ? w1a : (m == 1) ? w1b : w1c;
    w1h[i] = f2b(src[(size_t)s * (384 * 128) + (size_t)k * 128 + n]);
  } else if (i < N1 + N2) {
    int j = i - N1;
    int g = j / (128 * 128);
    int rem = j - g * (128 * 128);
    int n = rem / 128, k = rem - n * 128;
    int m = g / 6, s = g - m * 6;
    const float* src = (m == 0) ? w2a : (m == 1) ? w2b : w2c;
    float f = src[(size_t)s * (128 * 128) + (size_t)k * 128 + n];
    short hi = f2b(f);
    w2h[j] = hi;
    w2l[j] = f2b(f - b2f(hi));
  }
}

__global__ void prep_deg(const int* mr, const int* wrcv, int* degm, int* degw) {
  int i = blockIdx.x * 256 + threadIdx.x;
  if (i < EM_N) atomicAdd(&degm[mr[i]], 1);
  else if (i < EM_N + EW_N) atomicAdd(&degw[wrcv[i - EM_N]], 1);
}

__global__ void prep_inv(const int* degm, const int* degw, float* invm, float* invw) {
  int i = blockIdx.x * 256 + threadIdx.x;
  if (i < NNODE) {
    invm[i] = 1.0f / fmaxf((float)degm[i], 1.0f);
    invw[i] = 1.0f / fmaxf((float)degw[i], 1.0f);
  }
}

extern "C" void kernel_launch(void* const* d_in, const int* in_sizes, int n_in,
                              void* d_out, int out_size, void* d_ws, size_t ws_size,
                              hipStream_t stream) {
  (void)in_sizes; (void)n_in; (void)out_size; (void)ws_size;
  const float* x_in   = (const float*)d_in[0];
  const float* mea_in = (const float*)d_in[1];
  const float* wea_in = (const float*)d_in[2];
  const int*   mei    = (const int*)d_in[3];
  const int*   wei    = (const int*)d_in[4];
  const float* W1s[3] = { (const float*)d_in[5],  (const float*)d_in[11], (const float*)d_in[17] };
  const float* B1s[3] = { (const float*)d_in[6],  (const float*)d_in[12], (const float*)d_in[18] };
  const float* W2s[3] = { (const float*)d_in[7],  (const float*)d_in[13], (const float*)d_in[19] };
  const float* B2s[3] = { (const float*)d_in[8],  (const float*)d_in[14], (const float*)d_in[20] };
  const float* Gs[3]  = { (const float*)d_in[9],  (const float*)d_in[15], (const float*)d_in[21] };
  const float* Be[3]  = { (const float*)d_in[10], (const float*)d_in[16], (const float*)d_in[22] };

  float* xo  = (float*)d_out;
  float* meo = xo  + (size_t)NNODE * LDIM;
  float* weo = meo + (size_t)EM_N * LDIM;

  float* msum = (float*)d_ws;
  float* wsum = msum + (size_t)NNODE * LDIM;
  int*   degm = (int*)(wsum + (size_t)NNODE * LDIM);
  int*   degw = degm + NNODE;
  float* invm = (float*)(degw + NNODE);
  float* invw = invm + NNODE;
  short* w1h  = (short*)(invw + NNODE);
  short* w2h  = w1h + (size_t)18 * 128 * 384;
  short* w2l  = w2h + (size_t)18 * 128 * 128;

  size_t zbytes = (size_t)2 * NNODE * LDIM * 4 + (size_t)2 * NNODE * 4;
  hipMemsetAsync(d_ws, 0, zbytes, stream);

  {
    int tot = 18 * 128 * 384 + 18 * 128 * 128;
    prep_weights<<<dim3((tot + 255) / 256), 256, 0, stream>>>(
        W1s[0], W1s[1], W1s[2], W2s[0], W2s[1], W2s[2], w1h, w2h, w2l);
  }
  prep_deg<<<dim3((EM_N + EW_N + 255) / 256), 256, 0, stream>>>(mei + EM_N, wei + EW_N, degm, degw);
  prep_inv<<<dim3((NNODE + 255) / 256), 256, 0, stream>>>(degm, degw, invm, invw);

  const int MB = (EM_N + 127) / 128;   // 782
  const int WB = (EW_N + 127) / 128;   // 196
  const int NB = (NNODE + 127) / 128;  // 157

  const float* xc = x_in;
  const float* mc = mea_in;
  const float* wc = wea_in;

  for (int s = 0; s < NSTEP; ++s) {
    MlpParams pm{}, pw{}, pn{};

    pm.x = xc; pm.attrIn = mc; pm.attrOut = meo;
    pm.src = mei; pm.dst = mei + EM_N;
    pm.sum1 = msum;
    pm.W1H = w1h + (size_t)(0 * 6 + s) * 128 * 384;
    pm.W2H = w2h + (size_t)(0 * 6 + s) * 128 * 128;
    pm.W2L = w2l + (size_t)(0 * 6 + s) * 128 * 128;
    pm.b1 = B1s[0] + s * LDIM; pm.b2 = B2s[0] + s * LDIM;
    pm.gam = Gs[0] + s * LDIM; pm.bet = Be[0] + s * LDIM;
    pm.nRows = EM_N;

    pw.x = xc; pw.attrIn = wc; pw.attrOut = weo;
    pw.src = wei; pw.dst = wei + EW_N;
    pw.sum1 = wsum;
    pw.W1H = w1h + (size_t)(1 * 6 + s) * 128 * 384;
    pw.W2H = w2h + (size_t)(1 * 6 + s) * 128 * 128;
    pw.W2L = w2l + (size_t)(1 * 6 + s) * 128 * 128;
    pw.b1 = B1s[1] + s * LDIM; pw.b2 = B2s[1] + s * LDIM;
    pw.gam = Gs[1] + s * LDIM; pw.bet = Be[1] + s * LDIM;
    pw.nRows = EW_N;

    mlp_kernel<true><<<dim3(MB + WB), 256, 0, stream>>>(pm, pw, MB);

    pn.x = xc; pn.attrIn = xc; pn.attrOut = xo;
    pn.sum1 = msum; pn.sum2 = wsum; pn.inv1 = invm; pn.inv2 = invw;
    pn.W1H = w1h + (size_t)(2 * 6 + s) * 128 * 384;
    pn.W2H = w2h + (size_t)(2 * 6 + s) * 128 * 128;
    pn.W2L = w2l + (size_t)(2 * 6 + s) * 128 * 128;
    pn.b1 = B1s[2] + s * LDIM; pn.b2 = B2s[2] + s * LDIM;
    pn.gam = Gs[2] + s * LDIM; pn.bet = Be[2] + s * LDIM;
    pn.nRows = NNODE;

    mlp_kernel<false><<<dim3(NB), 256, 0, stream>>>(pn, pn, NB);

    xc = xo; mc = meo; wc = weo;
  }
}

// Round 8
// 919.555 us; speedup vs baseline: 1.1963x; 1.1963x over previous
//
#include <hip/hip_runtime.h>

constexpr int LDIM  = 128;
constexpr int NNODE = 20000;
constexpr int EM_N  = 100000;
constexpr int EW_N  = 25000;
constexpr int NSTEP = 6;

typedef short bf16x8 __attribute__((ext_vector_type(8)));
typedef short bf16x4 __attribute__((ext_vector_type(4)));
typedef float f32x4  __attribute__((ext_vector_type(4)));

struct MlpParams {
  const float* x;
  const float* attrIn;
  float*       attrOut;
  const int*   src;
  const int*   dst;
  float*       sum1;    // edge: scatter target; node: mesh sum (zeroed after read)
  float*       sum2;    // node: world sum (zeroed after read)
  const float* inv1;
  const float* inv2;
  const short* W1H;     // bf16 [128 n][384 k]
  const short* W2H;     // bf16 [128 n][128 k]
  const float* b1;
  const float* b2;
  const float* gam;
  const float* bet;
  int nRows;
};

__device__ __forceinline__ short f2b(float f) {
  unsigned int u = __float_as_uint(f);
  u = (u + 0x7fffu + ((u >> 16) & 1u)) >> 16;
  return (short)u;
}
__device__ __forceinline__ float b2f(short s) {
  return __uint_as_float(((unsigned int)(unsigned short)s) << 16);
}
__device__ __forceinline__ bf16x4 cvt4(float4 a, float sc) {
  bf16x4 o;
  o[0] = f2b(a.x * sc); o[1] = f2b(a.y * sc);
  o[2] = f2b(a.z * sc); o[3] = f2b(a.w * sc);
  return o;
}

// R6 structure with two LDS cuts for 3 blocks/CU (51 KB):
//  (1) Abuf aliased into Hbuf storage (Abuf dead after last phase-1 MFMA;
//      barrier before H-write). Zero register cost.
//  (2) W2 single bf16 (W2-lo dropped — R6 showed absmax unchanged at 0.0625
//      when W1-lo was dropped; activation rounds dominate). Blo deleted,
//      phase-2 MFMAs halved.
// acc still dies at the H-write (R7's spill lesson: never hold acc+acc2 live).
template<bool IS_EDGE>
__launch_bounds__(256, 3)
__global__ void mlp_kernel(MlpParams pmA, MlpParams pmB, int blocksA) {
  const bool isA = (int)blockIdx.x < blocksA;
  const MlpParams P = isA ? pmA : pmB;
  const int bid  = isA ? (int)blockIdx.x : (int)blockIdx.x - blocksA;
  const int row0 = bid * 128;

  __shared__ __align__(16) short Hbuf[128][136];  // stride 272B: aligned + 2-way banks
  __shared__ __align__(16) short Bhi[128][40];    // W1/W2 chunk staging
  __shared__ float b1s[128], b2s[128], gs[128], bes[128];
  __shared__ int   idxa[128], idxb[128];
  __shared__ float inv1s[128], inv2s[128];
  __shared__ float sumL[2][128], sqL[2][128];
  __shared__ float muL[128], rsL[128];

  // Abuf aliases the first 10.24 KB of Hbuf (dead by the time H is written)
  short (*Abuf)[40] = (short (*)[40])(&Hbuf[0][0]);

  const int t = threadIdx.x;

  if (t < 128) {
    b1s[t] = P.b1[t];
    gs[t]  = P.gam[t];
    if (IS_EDGE) {
      int r = row0 + t;
      idxa[t] = (r < P.nRows) ? P.src[r] : 0;
    } else {
      int r = min(row0 + t, P.nRows - 1);
      inv1s[t] = P.inv1[r];
    }
  } else {
    int t2 = t - 128;
    b2s[t2] = P.b2[t2];
    bes[t2] = P.bet[t2];
    if (IS_EDGE) {
      int r = row0 + t2;
      idxb[t2] = (r < P.nRows) ? P.dst[r] : 0;
    } else {
      int r = min(row0 + t2, P.nRows - 1);
      inv2s[t2] = P.inv2[r];
    }
  }
  __syncthreads();   // idx/inv tables ready (needed for prefetch base setup)

  const int l   = t & 63;
  const int wid = t >> 6;
  const int wr  = wid >> 1, wcc = wid & 1;
  const int lr  = l & 15,  lg  = l >> 4;

  const int  srow  = t >> 1, sh = t & 1;   // staging row assignment (2 thr/row)
  const int  sgRow = row0 + srow;
  const bool sval  = sgRow < P.nRows;
  const int  sgC   = sval ? sgRow : 0;
  const float vmask = sval ? 1.f : 0.f;

  // per-thread A base pointers for the 3 input segments (incl. sh offset)
  const float* base0; const float* base1; const float* base2;
  float sc1v = vmask, sc2v = vmask;
  if (IS_EDGE) {
    base0 = P.x + (size_t)idxa[srow] * LDIM + sh * 16;
    base1 = P.x + (size_t)idxb[srow] * LDIM + sh * 16;
    base2 = P.attrIn + (size_t)sgC * LDIM + sh * 16;
  } else {
    base0 = P.x    + (size_t)sgC * LDIM + sh * 16;
    base1 = P.sum1 + (size_t)sgC * LDIM + sh * 16;
    base2 = P.sum2 + (size_t)sgC * LDIM + sh * 16;
    sc1v = inv1s[srow] * vmask;
    sc2v = inv2s[srow] * vmask;
  }

  // weight staging assignment (2 thr/row over 128 n-rows)
  const int wrow = t >> 1, wsh = t & 1;
  const short* w1base = P.W1H + (size_t)wrow * 384 + wsh * 16;

  f32x4 acc[4][4];
#pragma unroll
  for (int i = 0; i < 4; ++i)
#pragma unroll
    for (int j = 0; j < 4; ++j) acc[i][j] = f32x4{0.f, 0.f, 0.f, 0.f};

  // named prefetch registers
  float4 pA0, pA1, pA2, pA3;
  bf16x8 pW0, pW1;
  {
    const float4* bp = (const float4*)base0;
    pA0 = bp[0]; pA1 = bp[1]; pA2 = bp[2]; pA3 = bp[3];
    pW0 = *(const bf16x8*)w1base;
    pW1 = *(const bf16x8*)(w1base + 8);
  }

  // ---------------- phase 1: H = relu(A @ W1 + b1), K = 384 ----------------
#pragma unroll
  for (int kc = 0; kc < 12; ++kc) {
    const int seg = kc >> 2, part = kc & 3;
    if (kc > 0) __syncthreads();          // staging buffers free
    {
      const float scK = (seg == 0) ? vmask : (seg == 1) ? sc1v : sc2v;
      *(bf16x4*)&Abuf[srow][sh * 16 + 0]  = cvt4(pA0, scK);
      *(bf16x4*)&Abuf[srow][sh * 16 + 4]  = cvt4(pA1, scK);
      *(bf16x4*)&Abuf[srow][sh * 16 + 8]  = cvt4(pA2, scK);
      *(bf16x4*)&Abuf[srow][sh * 16 + 12] = cvt4(pA3, scK);
      *(bf16x8*)&Bhi[wrow][wsh * 16]     = pW0;
      *(bf16x8*)&Bhi[wrow][wsh * 16 + 8] = pW1;
      if constexpr (!IS_EDGE) {
        if (seg != 0 && sval) {           // zero-after-read (value already in regs)
          float4 z = {0.f, 0.f, 0.f, 0.f};
          float4* zp = (float4*)((seg == 1 ? base1 : base2) + part * 32);
          zp[0] = z; zp[1] = z; zp[2] = z; zp[3] = z;
        }
      }
    }
    __syncthreads();                      // data ready
    if (kc < 11) {                        // issue next-chunk loads; fly over MFMAs
      const int kn = kc + 1, segn = kn >> 2, partn = kn & 3;
      const float4* bp = (const float4*)((segn == 0 ? base0 : segn == 1 ? base1 : base2) + partn * 32);
      pA0 = bp[0]; pA1 = bp[1]; pA2 = bp[2]; pA3 = bp[3];
      pW0 = *(const bf16x8*)(w1base + kn * 32);
      pW1 = *(const bf16x8*)(w1base + kn * 32 + 8);
    }
    bf16x8 av[4], bh[4];
#pragma unroll
    for (int mi = 0; mi < 4; ++mi)
      av[mi] = *(const bf16x8*)&Abuf[wr * 64 + mi * 16 + lr][lg * 8];
#pragma unroll
    for (int ni = 0; ni < 4; ++ni)
      bh[ni] = *(const bf16x8*)&Bhi[wcc * 64 + ni * 16 + lr][lg * 8];
#pragma unroll
    for (int mi = 0; mi < 4; ++mi)
#pragma unroll
      for (int ni = 0; ni < 4; ++ni)
        acc[mi][ni] = __builtin_amdgcn_mfma_f32_16x16x32_bf16(av[mi], bh[ni], acc[mi][ni], 0, 0, 0);
  }

  __syncthreads();   // all phase-1 Abuf reads done: safe to overwrite via Hbuf

  // write H = relu(acc + b1) to LDS as bf16 (acc dies here — R7 lesson)
#pragma unroll
  for (int rt = 0; rt < 4; ++rt)
#pragma unroll
    for (int ct = 0; ct < 4; ++ct) {
      const int cc = wcc * 64 + ct * 16 + lr;
      const float bb = b1s[cc];
#pragma unroll
      for (int q = 0; q < 4; ++q) {
        const int rr = wr * 64 + rt * 16 + lg * 4 + q;
        Hbuf[rr][cc] = f2b(fmaxf(acc[rt][ct][q] + bb, 0.f));
      }
    }

  // ---------------- phase 2: OUT = H @ W2 + b2, K = 128 ----------------
  f32x4 acc2[4][4];
#pragma unroll
  for (int i = 0; i < 4; ++i)
#pragma unroll
    for (int j = 0; j < 4; ++j) acc2[i][j] = f32x4{0.f, 0.f, 0.f, 0.f};

  const short* w2base = P.W2H + (size_t)wrow * 128 + wsh * 16;
  bf16x8 q0 = *(const bf16x8*)w2base;
  bf16x8 q1 = *(const bf16x8*)(w2base + 8);

#pragma unroll
  for (int kc = 0; kc < 4; ++kc) {
    __syncthreads();   // kc=0: H writes + phase-1 Bhi readers done; else prev readers done
    {
      *(bf16x8*)&Bhi[wrow][wsh * 16]     = q0;
      *(bf16x8*)&Bhi[wrow][wsh * 16 + 8] = q1;
    }
    __syncthreads();
    if (kc < 3) {
      q0 = *(const bf16x8*)(w2base + (kc + 1) * 32);
      q1 = *(const bf16x8*)(w2base + (kc + 1) * 32 + 8);
    }
    bf16x8 av2[4], bh2[4];
#pragma unroll
    for (int rt = 0; rt < 4; ++rt)
      av2[rt] = *(const bf16x8*)&Hbuf[wr * 64 + rt * 16 + lr][kc * 32 + lg * 8];
#pragma unroll
    for (int ct = 0; ct < 4; ++ct)
      bh2[ct] = *(const bf16x8*)&Bhi[wcc * 64 + ct * 16 + lr][lg * 8];
#pragma unroll
    for (int rt = 0; rt < 4; ++rt)
#pragma unroll
      for (int ct = 0; ct < 4; ++ct)
        acc2[rt][ct] = __builtin_amdgcn_mfma_f32_16x16x32_bf16(av2[rt], bh2[ct], acc2[rt][ct], 0, 0, 0);
  }

  // ---------------- f32 epilogue: b2 + LN stats from registers ----------------
  float s1[4][4], s2[4][4];
#pragma unroll
  for (int rt = 0; rt < 4; ++rt)
#pragma unroll
    for (int q = 0; q < 4; ++q) { s1[rt][q] = 0.f; s2[rt][q] = 0.f; }
#pragma unroll
  for (int rt = 0; rt < 4; ++rt)
#pragma unroll
    for (int ct = 0; ct < 4; ++ct) {
      const float bb = b2s[wcc * 64 + ct * 16 + lr];
#pragma unroll
      for (int q = 0; q < 4; ++q) {
        float v = acc2[rt][ct][q] + bb;
        acc2[rt][ct][q] = v;
        s1[rt][q] += v;
        s2[rt][q] += v * v;
      }
    }
#pragma unroll
  for (int m = 1; m < 16; m <<= 1) {
#pragma unroll
    for (int rt = 0; rt < 4; ++rt)
#pragma unroll
      for (int q = 0; q < 4; ++q) {
        s1[rt][q] += __shfl_xor(s1[rt][q], m);
        s2[rt][q] += __shfl_xor(s2[rt][q], m);
      }
  }
  __syncthreads();
  {
    const int rt = lr >> 2, q = lr & 3;
    const int rr = wr * 64 + rt * 16 + lg * 4 + q;
    sumL[wcc][rr] = s1[rt][q];
    sqL[wcc][rr]  = s2[rt][q];
  }
  __syncthreads();
  if (t < 128) {
    const float tot = sumL[0][t] + sumL[1][t];
    const float tsq = sqL[0][t] + sqL[1][t];
    const float mu  = tot * (1.0f / 128.0f);
    const float var = tsq * (1.0f / 128.0f) - mu * mu;
    muL[t] = mu;
    rsL[t] = rsqrtf(var + 1e-5f);
  }
  __syncthreads();

  // ---------------- normalize + residual + store + (edge) scatter-add ----------------
#pragma unroll
  for (int rt = 0; rt < 4; ++rt) {
#pragma unroll
    for (int q = 0; q < 4; ++q) {
      const int rr = wr * 64 + rt * 16 + lg * 4 + q;
      const int grow = row0 + rr;
      if (grow < P.nRows) {
        const float mu = muL[rr], rs = rsL[rr];
        const float* rin = P.attrIn + (size_t)grow * LDIM;
        float* rout = P.attrOut + (size_t)grow * LDIM;
        float* ssum = nullptr;
        if (IS_EDGE) ssum = P.sum1 + (size_t)idxb[rr] * LDIM;
#pragma unroll
        for (int ct = 0; ct < 4; ++ct) {
          const int cc = wcc * 64 + ct * 16 + lr;
          const float o = gs[cc] * (acc2[rt][ct][q] - mu) * rs + bes[cc] + rin[cc];
          rout[cc] = o;
          if (IS_EDGE) atomicAdd(ssum + cc, o);
        }
      }
    }
  }
}

// ---- prep kernels ----
__global__ void prep_weights(const float* w1a, const float* w1b, const float* w1c,
                             const float* w2a, const float* w2b, const float* w2c,
                             short* w1h, short* w2h) {
  int i = blockIdx.x * 256 + threadIdx.x;
  constexpr int N1 = 18 * 128 * 384;
  constexpr int N2 = 18 * 128 * 128;
  if (i < N1) {
    int g = i / (128 * 384);
    int rem = i - g * (128 * 384);
    int n = rem / 384, k = rem - n * 384;
    int m = g / 6, s = g - m * 6;
    const float* src = (m == 0) ? w1a : (m == 1) ? w1b : w1c;
    w1h[i] = f2b(src[(size_t)s * (384 * 128) + (size_t)k * 128 + n]);
  } else if (i < N1 + N2) {
    int j = i - N1;
    int g = j / (128 * 128);
    int rem = j - g * (128 * 128);
    int n = rem / 128, k = rem - n * 128;
    int m = g / 6, s = g - m * 6;
    const float* src = (m == 0) ? w2a : (m == 1) ? w2b : w2c;
    w2h[j] = f2b(src[(size_t)s * (128 * 128) + (size_t)k * 128 + n]);
  }
}

__global__ void prep_deg(const int* mr, const int* wrcv, int* degm, int* degw) {
  int i = blockIdx.x * 256 + threadIdx.x;
  if (i < EM_N) atomicAdd(&degm[mr[i]], 1);
  else if (i < EM_N + EW_N) atomicAdd(&degw[wrcv[i - EM_N]], 1);
}

__global__ void prep_inv(const int* degm, const int* degw, float* invm, float* invw) {
  int i = blockIdx.x * 256 + threadIdx.x;
  if (i < NNODE) {
    invm[i] = 1.0f / fmaxf((float)degm[i], 1.0f);
    invw[i] = 1.0f / fmaxf((float)degw[i], 1.0f);
  }
}

extern "C" void kernel_launch(void* const* d_in, const int* in_sizes, int n_in,
                              void* d_out, int out_size, void* d_ws, size_t ws_size,
                              hipStream_t stream) {
  (void)in_sizes; (void)n_in; (void)out_size; (void)ws_size;
  const float* x_in   = (const float*)d_in[0];
  const float* mea_in = (const float*)d_in[1];
  const float* wea_in = (const float*)d_in[2];
  const int*   mei    = (const int*)d_in[3];
  const int*   wei    = (const int*)d_in[4];
  const float* W1s[3] = { (const float*)d_in[5],  (const float*)d_in[11], (const float*)d_in[17] };
  const float* B1s[3] = { (const float*)d_in[6],  (const float*)d_in[12], (const float*)d_in[18] };
  const float* W2s[3] = { (const float*)d_in[7],  (const float*)d_in[13], (const float*)d_in[19] };
  const float* B2s[3] = { (const float*)d_in[8],  (const float*)d_in[14], (const float*)d_in[20] };
  const float* Gs[3]  = { (const float*)d_in[9],  (const float*)d_in[15], (const float*)d_in[21] };
  const float* Be[3]  = { (const float*)d_in[10], (const float*)d_in[16], (const float*)d_in[22] };

  float* xo  = (float*)d_out;
  float* meo = xo  + (size_t)NNODE * LDIM;
  float* weo = meo + (size_t)EM_N * LDIM;

  float* msum = (float*)d_ws;
  float* wsum = msum + (size_t)NNODE * LDIM;
  int*   degm = (int*)(wsum + (size_t)NNODE * LDIM);
  int*   degw = degm + NNODE;
  float* invm = (float*)(degw + NNODE);
  float* invw = invm + NNODE;
  short* w1h  = (short*)(invw + NNODE);
  short* w2h  = w1h + (size_t)18 * 128 * 384;

  size_t zbytes = (size_t)2 * NNODE * LDIM * 4 + (size_t)2 * NNODE * 4;
  hipMemsetAsync(d_ws, 0, zbytes, stream);

  {
    int tot = 18 * 128 * 384 + 18 * 128 * 128;
    prep_weights<<<dim3((tot + 255) / 256), 256, 0, stream>>>(
        W1s[0], W1s[1], W1s[2], W2s[0], W2s[1], W2s[2], w1h, w2h);
  }
  prep_deg<<<dim3((EM_N + EW_N + 255) / 256), 256, 0, stream>>>(mei + EM_N, wei + EW_N, degm, degw);
  prep_inv<<<dim3((NNODE + 255) / 256), 256, 0, stream>>>(degm, degw, invm, invw);

  const int MB = (EM_N + 127) / 128;   // 782
  const int WB = (EW_N + 127) / 128;   // 196
  const int NB = (NNODE + 127) / 128;  // 157

  const float* xc = x_in;
  const float* mc = mea_in;
  const float* wc = wea_in;

  for (int s = 0; s < NSTEP; ++s) {
    MlpParams pm{}, pw{}, pn{};

    pm.x = xc; pm.attrIn = mc; pm.attrOut = meo;
    pm.src = mei; pm.dst = mei + EM_N;
    pm.sum1 = msum;
    pm.W1H = w1h + (size_t)(0 * 6 + s) * 128 * 384;
    pm.W2H = w2h + (size_t)(0 * 6 + s) * 128 * 128;
    pm.b1 = B1s[0] + s * LDIM; pm.b2 = B2s[0] + s * LDIM;
    pm.gam = Gs[0] + s * LDIM; pm.bet = Be[0] + s * LDIM;
    pm.nRows = EM_N;

    pw.x = xc; pw.attrIn = wc; pw.attrOut = weo;
    pw.src = wei; pw.dst = wei + EW_N;
    pw.sum1 = wsum;
    pw.W1H = w1h + (size_t)(1 * 6 + s) * 128 * 384;
    pw.W2H = w2h + (size_t)(1 * 6 + s) * 128 * 128;
    pw.b1 = B1s[1] + s * LDIM; pw.b2 = B2s[1] + s * LDIM;
    pw.gam = Gs[1] + s * LDIM; pw.bet = Be[1] + s * LDIM;
    pw.nRows = EW_N;

    mlp_kernel<true><<<dim3(MB + WB), 256, 0, stream>>>(pm, pw, MB);

    pn.x = xc; pn.attrIn = xc; pn.attrOut = xo;
    pn.sum1 = msum; pn.sum2 = wsum; pn.inv1 = invm; pn.inv2 = invw;
    pn.W1H = w1h + (size_t)(2 * 6 + s) * 128 * 384;
    pn.W2H = w2h + (size_t)(2 * 6 + s) * 128 * 128;
    pn.b1 = B1s[2] + s * LDIM; pn.b2 = B2s[2] + s * LDIM;
    pn.gam = Gs[2] + s * LDIM; pn.bet = Be[2] + s * LDIM;
    pn.nRows = NNODE;

    mlp_kernel<false><<<dim3(NB), 256, 0, stream>>>(pn, pn, NB);

    xc = xo; mc = meo; wc = weo;
  }
}